// Round 3
// baseline (247.409 us; speedup 1.0000x reference)
//
#include <hip/hip_runtime.h>
#include <math.h>

#define BATCH   2048
#define NPTS    4096
#define THREADS 256
#define WTHRESH 0.5f
#define EPS     1e-5

// ---------------------------------------------------------------------------
// Per-thread accumulation of the 16 sufficient statistics over 16 points.
// acc layout: [0]=W  [1..3]=sum w*src  [4..6]=sum w*tgt  [7..15]=sum w*src_i*tgt_j
// ---------------------------------------------------------------------------
__device__ __forceinline__ void accumulate(const float* __restrict__ sb,
                                           const float* __restrict__ tb,
                                           const float* __restrict__ wb,
                                           float* acc) {
  const int t = threadIdx.x;
#pragma unroll
  for (int i = 0; i < 16; ++i) acc[i] = 0.f;

#pragma unroll
  for (int k = 0; k < 4; ++k) {
    const int p0 = (t + k * THREADS) * 4;  // 4 consecutive points
    float4 w4 = *(const float4*)(wb + p0);
    const float4* sp = (const float4*)(sb + (size_t)p0 * 3);
    float4 s0 = sp[0], s1 = sp[1], s2 = sp[2];
    const float4* tp = (const float4*)(tb + (size_t)p0 * 3);
    float4 r0 = tp[0], r1 = tp[1], r2 = tp[2];

    float ww[4] = {w4.x, w4.y, w4.z, w4.w};
    float ps[4][3] = {{s0.x, s0.y, s0.z}, {s0.w, s1.x, s1.y},
                      {s1.z, s1.w, s2.x}, {s2.y, s2.z, s2.w}};
    float qs[4][3] = {{r0.x, r0.y, r0.z}, {r0.w, r1.x, r1.y},
                      {r1.z, r1.w, r2.x}, {r2.y, r2.z, r2.w}};
#pragma unroll
    for (int i = 0; i < 4; ++i) {
      float w = (ww[i] < WTHRESH) ? 0.f : ww[i];
      acc[0] += w;
      float wp0 = w * ps[i][0], wp1 = w * ps[i][1], wp2 = w * ps[i][2];
      acc[1] += wp0; acc[2] += wp1; acc[3] += wp2;
      acc[4] += w * qs[i][0]; acc[5] += w * qs[i][1]; acc[6] += w * qs[i][2];
      acc[7]  += wp0 * qs[i][0]; acc[8]  += wp0 * qs[i][1]; acc[9]  += wp0 * qs[i][2];
      acc[10] += wp1 * qs[i][0]; acc[11] += wp1 * qs[i][1]; acc[12] += wp1 * qs[i][2];
      acc[13] += wp2 * qs[i][0]; acc[14] += wp2 * qs[i][1]; acc[15] += wp2 * qs[i][2];
    }
  }
}

// Block-wide reduction of 16 floats; valid in acc[] of thread 0 afterwards.
__device__ __forceinline__ void reduce_block16(float* acc, float* red /*64 floats*/) {
#pragma unroll
  for (int off = 32; off > 0; off >>= 1) {
#pragma unroll
    for (int i = 0; i < 16; ++i) acc[i] += __shfl_down(acc[i], off, 64);
  }
  const int wave = threadIdx.x >> 6;
  const int lane = threadIdx.x & 63;
  if (lane == 0) {
#pragma unroll
    for (int i = 0; i < 16; ++i) red[wave * 16 + i] = acc[i];
  }
  __syncthreads();
  if (threadIdx.x == 0) {
#pragma unroll
    for (int w = 1; w < 4; ++w)
#pragma unroll
      for (int i = 0; i < 16; ++i) acc[i] += red[w * 16 + i];
  }
}

// ---------------------------------------------------------------------------
// fp64 3x3 Kabsch solve from the 16 statistics.
// R = v1 u1^T + v2 u2^T + det(V) * v3 (u1 x u2)^T  -- no division by s3,
// no explicit sign(det H): algebraically identical to V diag(1,1,sgn) U^T.
// ---------------------------------------------------------------------------
__device__ void solve_from_acc(const float* acc, float* R9, float* t3) {
  double W = acc[0];
  double inv = 1.0 / (W + EPS);
  double sc[3], tc[3];
#pragma unroll
  for (int i = 0; i < 3; ++i) { sc[i] = (double)acc[1 + i] * inv; tc[i] = (double)acc[4 + i] * inv; }
  double ssum = W * inv;

  double H[3][3];
#pragma unroll
  for (int i = 0; i < 3; ++i)
#pragma unroll
    for (int j = 0; j < 3; ++j)
      H[i][j] = (double)acc[7 + 3 * i + j] * inv - sc[i] * tc[j] * (2.0 - ssum);

  // A = H^T H (symmetric PSD)
  double A[3][3];
#pragma unroll
  for (int i = 0; i < 3; ++i)
#pragma unroll
    for (int j = 0; j < 3; ++j)
      A[i][j] = H[0][i] * H[0][j] + H[1][i] * H[1][j] + H[2][i] * H[2][j];

  double V[3][3] = {{1, 0, 0}, {0, 1, 0}, {0, 0, 1}};

  // Cyclic Jacobi eigen-decomposition (quadratic convergence; 3x3).
  const int PQ[3][2] = {{0, 1}, {0, 2}, {1, 2}};
  for (int sweep = 0; sweep < 15; ++sweep) {
    double off = fabs(A[0][1]) + fabs(A[0][2]) + fabs(A[1][2]);
    if (off < 1e-28) break;
#pragma unroll
    for (int r = 0; r < 3; ++r) {
      int p = PQ[r][0], q = PQ[r][1];
      double apq = A[p][q];
      if (fabs(apq) < 1e-300) continue;
      double theta = (A[q][q] - A[p][p]) / (2.0 * apq);
      double tj = copysign(1.0, theta) / (fabs(theta) + sqrt(theta * theta + 1.0));
      double c = 1.0 / sqrt(tj * tj + 1.0);
      double sn = tj * c;
#pragma unroll
      for (int k = 0; k < 3; ++k) {   // columns
        double akp = A[k][p], akq = A[k][q];
        A[k][p] = c * akp - sn * akq;
        A[k][q] = sn * akp + c * akq;
      }
#pragma unroll
      for (int k = 0; k < 3; ++k) {   // rows
        double apk = A[p][k], aqk = A[q][k];
        A[p][k] = c * apk - sn * aqk;
        A[q][k] = sn * apk + c * aqk;
      }
#pragma unroll
      for (int k = 0; k < 3; ++k) {   // accumulate V
        double vkp = V[k][p], vkq = V[k][q];
        V[k][p] = c * vkp - sn * vkq;
        V[k][q] = sn * vkp + c * vkq;
      }
    }
  }

  // Sort eigenpairs descending.
  double e[3] = {A[0][0], A[1][1], A[2][2]};
  int i0 = 0, i1 = 1, i2 = 2, tswap;
  if (e[i0] < e[i1]) { tswap = i0; i0 = i1; i1 = tswap; }
  if (e[i0] < e[i2]) { tswap = i0; i0 = i2; i2 = tswap; }
  if (e[i1] < e[i2]) { tswap = i1; i1 = i2; i2 = tswap; }

  double v1[3], v2[3], v3[3];
#pragma unroll
  for (int k = 0; k < 3; ++k) { v1[k] = V[k][i0]; v2[k] = V[k][i1]; v3[k] = V[k][i2]; }

  // u1 = normalize(H v1)
  double u1[3], u2[3];
#pragma unroll
  for (int k = 0; k < 3; ++k) u1[k] = H[k][0] * v1[0] + H[k][1] * v1[1] + H[k][2] * v1[2];
  double n1 = sqrt(u1[0] * u1[0] + u1[1] * u1[1] + u1[2] * u1[2]);
  if (n1 > 1e-150) { double r = 1.0 / n1; u1[0] *= r; u1[1] *= r; u1[2] *= r; }
  else { u1[0] = 1.0; u1[1] = 0.0; u1[2] = 0.0; }

  // u2 = normalize(H v2 orthogonalized against u1)
#pragma unroll
  for (int k = 0; k < 3; ++k) u2[k] = H[k][0] * v2[0] + H[k][1] * v2[1] + H[k][2] * v2[2];
  double d12 = u1[0] * u2[0] + u1[1] * u2[1] + u1[2] * u2[2];
#pragma unroll
  for (int k = 0; k < 3; ++k) u2[k] -= d12 * u1[k];
  double n2 = sqrt(u2[0] * u2[0] + u2[1] * u2[1] + u2[2] * u2[2]);
  if (n2 > 1e-150) { double r = 1.0 / n2; u2[0] *= r; u2[1] *= r; u2[2] *= r; }
  else {
    // any unit vector orthogonal to u1
    double ax = fabs(u1[0]);
    double t0 = (ax < 0.9) ? 1.0 : 0.0, t1v = (ax < 0.9) ? 0.0 : 1.0;
    u2[0] = t0 - (t0 * u1[0] + t1v * u1[1]) * u1[0];
    u2[1] = t1v - (t0 * u1[0] + t1v * u1[1]) * u1[1];
    u2[2] = -(t0 * u1[0] + t1v * u1[1]) * u1[2];
    double nn = sqrt(u2[0] * u2[0] + u2[1] * u2[1] + u2[2] * u2[2]);
    u2[0] /= nn; u2[1] /= nn; u2[2] /= nn;
  }

  // w3 = u1 x u2 (unit, right-handed)
  double w3[3] = {u1[1] * u2[2] - u1[2] * u2[1],
                  u1[2] * u2[0] - u1[0] * u2[2],
                  u1[0] * u2[1] - u1[1] * u2[0]};

  // det(V) with reordered columns = v1 . (v2 x v3)
  double cx = v2[1] * v3[2] - v2[2] * v3[1];
  double cy = v2[2] * v3[0] - v2[0] * v3[2];
  double cz = v2[0] * v3[1] - v2[1] * v3[0];
  double detV = v1[0] * cx + v1[1] * cy + v1[2] * cz;
  detV = (detV >= 0.0) ? 1.0 : -1.0;

  double R[3][3];
#pragma unroll
  for (int i = 0; i < 3; ++i)
#pragma unroll
    for (int j = 0; j < 3; ++j)
      R[i][j] = v1[i] * u1[j] + v2[i] * u2[j] + detV * v3[i] * w3[j];

#pragma unroll
  for (int i = 0; i < 3; ++i) {
#pragma unroll
    for (int j = 0; j < 3; ++j) R9[3 * i + j] = (float)R[i][j];
    t3[i] = (float)(tc[i] - (R[i][0] * sc[0] + R[i][1] * sc[1] + R[i][2] * sc[2]));
  }
}

// ---------------------------------------------------------------------------
// Kernel 1: per-batch streaming reduction -> 16 partials per batch in d_ws.
// ---------------------------------------------------------------------------
__global__ __launch_bounds__(THREADS) void wp_reduce(const float* __restrict__ src,
                                                     const float* __restrict__ tgt,
                                                     const float* __restrict__ wts,
                                                     float* __restrict__ partials) {
  __shared__ float red[64];
  const int b = blockIdx.x;
  float acc[16];
  accumulate(src + (size_t)b * NPTS * 3, tgt + (size_t)b * NPTS * 3,
             wts + (size_t)b * NPTS, acc);
  reduce_block16(acc, red);
  if (threadIdx.x == 0) {
#pragma unroll
    for (int i = 0; i < 16; ++i) partials[b * 16 + i] = acc[i];
  }
}

// Kernel 2: one thread per batch does the fp64 3x3 solve.
__global__ void wp_solve(const float* __restrict__ partials, float* __restrict__ out) {
  const int b = blockIdx.x * blockDim.x + threadIdx.x;
  if (b >= BATCH) return;
  float acc[16];
#pragma unroll
  for (int i = 0; i < 16; ++i) acc[i] = partials[b * 16 + i];
  float R9[9], t3[3];
  solve_from_acc(acc, R9, t3);
#pragma unroll
  for (int i = 0; i < 9; ++i) out[(size_t)b * 9 + i] = R9[i];
#pragma unroll
  for (int i = 0; i < 3; ++i) out[(size_t)BATCH * 9 + (size_t)b * 3 + i] = t3[i];
}

// Fused fallback (used only if ws_size is too small for the partials).
__global__ __launch_bounds__(THREADS) void wp_fused(const float* __restrict__ src,
                                                    const float* __restrict__ tgt,
                                                    const float* __restrict__ wts,
                                                    float* __restrict__ out) {
  __shared__ float red[64];
  const int b = blockIdx.x;
  float acc[16];
  accumulate(src + (size_t)b * NPTS * 3, tgt + (size_t)b * NPTS * 3,
             wts + (size_t)b * NPTS, acc);
  reduce_block16(acc, red);
  if (threadIdx.x == 0) {
    float R9[9], t3[3];
    solve_from_acc(acc, R9, t3);
#pragma unroll
    for (int i = 0; i < 9; ++i) out[(size_t)b * 9 + i] = R9[i];
#pragma unroll
    for (int i = 0; i < 3; ++i) out[(size_t)BATCH * 9 + (size_t)b * 3 + i] = t3[i];
  }
}

extern "C" void kernel_launch(void* const* d_in, const int* in_sizes, int n_in,
                              void* d_out, int out_size, void* d_ws, size_t ws_size,
                              hipStream_t stream) {
  const float* src = (const float*)d_in[0];
  const float* tgt = (const float*)d_in[1];
  const float* wts = (const float*)d_in[2];
  float* out = (float*)d_out;

  if (ws_size >= (size_t)BATCH * 16 * sizeof(float)) {
    float* partials = (float*)d_ws;
    wp_reduce<<<BATCH, THREADS, 0, stream>>>(src, tgt, wts, partials);
    wp_solve<<<(BATCH + 255) / 256, 256, 0, stream>>>(partials, out);
  } else {
    wp_fused<<<BATCH, THREADS, 0, stream>>>(src, tgt, wts, out);
  }
}

// Round 5
// 243.606 us; speedup vs baseline: 1.0156x; 1.0156x over previous
//
#include <hip/hip_runtime.h>
#include <math.h>

#define BATCH   2048
#define NPTS    4096
#define THREADS 256
#define CHUNKS  4                    // blocks per batch
#define CPTS    (NPTS / CHUNKS)      // 1024 points per block
#define WTHRESH 0.5f
#define EPS     1e-5

// ---------------------------------------------------------------------------
// Per-thread accumulation of 16 sufficient statistics over 4 consecutive
// points: one float4 weight load + 3 float4 src + 3 float4 tgt, all issued
// back-to-back (single vmcnt wait) for maximum memory-level parallelism.
// acc: [0]=W [1..3]=sum w*src [4..6]=sum w*tgt [7..15]=sum w*src_i*tgt_j
// ---------------------------------------------------------------------------
__device__ __forceinline__ void accumulate4(const float* __restrict__ sb,
                                            const float* __restrict__ tb,
                                            const float* __restrict__ wb,
                                            float* acc) {
  const int p0 = threadIdx.x * 4;  // 4 consecutive points within the chunk
  float4 w4 = *(const float4*)(wb + p0);
  const float4* sp = (const float4*)(sb + (size_t)p0 * 3);
  float4 s0 = sp[0], s1 = sp[1], s2 = sp[2];
  const float4* tp = (const float4*)(tb + (size_t)p0 * 3);
  float4 r0 = tp[0], r1 = tp[1], r2 = tp[2];

  float ww[4] = {w4.x, w4.y, w4.z, w4.w};
  float ps[4][3] = {{s0.x, s0.y, s0.z}, {s0.w, s1.x, s1.y},
                    {s1.z, s1.w, s2.x}, {s2.y, s2.z, s2.w}};
  float qs[4][3] = {{r0.x, r0.y, r0.z}, {r0.w, r1.x, r1.y},
                    {r1.z, r1.w, r2.x}, {r2.y, r2.z, r2.w}};
#pragma unroll
  for (int i = 0; i < 16; ++i) acc[i] = 0.f;
#pragma unroll
  for (int i = 0; i < 4; ++i) {
    float w = (ww[i] < WTHRESH) ? 0.f : ww[i];
    acc[0] += w;
    float wp0 = w * ps[i][0], wp1 = w * ps[i][1], wp2 = w * ps[i][2];
    acc[1] += wp0; acc[2] += wp1; acc[3] += wp2;
    acc[4] += w * qs[i][0]; acc[5] += w * qs[i][1]; acc[6] += w * qs[i][2];
    acc[7]  += wp0 * qs[i][0]; acc[8]  += wp0 * qs[i][1]; acc[9]  += wp0 * qs[i][2];
    acc[10] += wp1 * qs[i][0]; acc[11] += wp1 * qs[i][1]; acc[12] += wp1 * qs[i][2];
    acc[13] += wp2 * qs[i][0]; acc[14] += wp2 * qs[i][1]; acc[15] += wp2 * qs[i][2];
  }
}

// Block-wide reduction of 16 floats; valid in acc[] of thread 0 afterwards.
__device__ __forceinline__ void reduce_block16(float* acc, float* red /*64 floats*/) {
#pragma unroll
  for (int off = 32; off > 0; off >>= 1) {
#pragma unroll
    for (int i = 0; i < 16; ++i) acc[i] += __shfl_down(acc[i], off, 64);
  }
  const int wave = threadIdx.x >> 6;
  const int lane = threadIdx.x & 63;
  if (lane == 0) {
#pragma unroll
    for (int i = 0; i < 16; ++i) red[wave * 16 + i] = acc[i];
  }
  __syncthreads();
  if (threadIdx.x == 0) {
#pragma unroll
    for (int w = 1; w < 4; ++w)
#pragma unroll
      for (int i = 0; i < 16; ++i) acc[i] += red[w * 16 + i];
  }
}

// ---------------------------------------------------------------------------
// fp64 3x3 Kabsch solve from the 16 statistics.
// R = v1 u1^T + v2 u2^T + det(V) * v3 (u1 x u2)^T
// ---------------------------------------------------------------------------
__device__ void solve_from_acc(const float* acc, float* R9, float* t3) {
  double W = acc[0];
  double inv = 1.0 / (W + EPS);
  double sc[3], tc[3];
#pragma unroll
  for (int i = 0; i < 3; ++i) { sc[i] = (double)acc[1 + i] * inv; tc[i] = (double)acc[4 + i] * inv; }
  double ssum = W * inv;

  double H[3][3];
#pragma unroll
  for (int i = 0; i < 3; ++i)
#pragma unroll
    for (int j = 0; j < 3; ++j)
      H[i][j] = (double)acc[7 + 3 * i + j] * inv - sc[i] * tc[j] * (2.0 - ssum);

  // A = H^T H (symmetric PSD)
  double A[3][3];
#pragma unroll
  for (int i = 0; i < 3; ++i)
#pragma unroll
    for (int j = 0; j < 3; ++j)
      A[i][j] = H[0][i] * H[0][j] + H[1][i] * H[1][j] + H[2][i] * H[2][j];

  double V[3][3] = {{1, 0, 0}, {0, 1, 0}, {0, 0, 1}};

  // Cyclic Jacobi eigen-decomposition; quadratic convergence, 8 sweeps cap.
  const int PQ[3][2] = {{0, 1}, {0, 2}, {1, 2}};
  for (int sweep = 0; sweep < 8; ++sweep) {
    double off = fabs(A[0][1]) + fabs(A[0][2]) + fabs(A[1][2]);
    if (off < 1e-26) break;
#pragma unroll
    for (int r = 0; r < 3; ++r) {
      int p = PQ[r][0], q = PQ[r][1];
      double apq = A[p][q];
      if (fabs(apq) < 1e-300) continue;
      double theta = (A[q][q] - A[p][p]) / (2.0 * apq);
      double tj = copysign(1.0, theta) / (fabs(theta) + sqrt(theta * theta + 1.0));
      double c = 1.0 / sqrt(tj * tj + 1.0);
      double sn = tj * c;
#pragma unroll
      for (int k = 0; k < 3; ++k) {   // columns
        double akp = A[k][p], akq = A[k][q];
        A[k][p] = c * akp - sn * akq;
        A[k][q] = sn * akp + c * akq;
      }
#pragma unroll
      for (int k = 0; k < 3; ++k) {   // rows
        double apk = A[p][k], aqk = A[q][k];
        A[p][k] = c * apk - sn * aqk;
        A[q][k] = sn * apk + c * aqk;
      }
#pragma unroll
      for (int k = 0; k < 3; ++k) {   // accumulate V
        double vkp = V[k][p], vkq = V[k][q];
        V[k][p] = c * vkp - sn * vkq;
        V[k][q] = sn * vkp + c * vkq;
      }
    }
  }

  // Sort eigenpairs descending.
  double e[3] = {A[0][0], A[1][1], A[2][2]};
  int i0 = 0, i1 = 1, i2 = 2, tswap;
  if (e[i0] < e[i1]) { tswap = i0; i0 = i1; i1 = tswap; }
  if (e[i0] < e[i2]) { tswap = i0; i0 = i2; i2 = tswap; }
  if (e[i1] < e[i2]) { tswap = i1; i1 = i2; i2 = tswap; }

  double v1[3], v2[3], v3[3];
#pragma unroll
  for (int k = 0; k < 3; ++k) { v1[k] = V[k][i0]; v2[k] = V[k][i1]; v3[k] = V[k][i2]; }

  // u1 = normalize(H v1)
  double u1[3], u2[3];
#pragma unroll
  for (int k = 0; k < 3; ++k) u1[k] = H[k][0] * v1[0] + H[k][1] * v1[1] + H[k][2] * v1[2];
  double n1 = sqrt(u1[0] * u1[0] + u1[1] * u1[1] + u1[2] * u1[2]);
  if (n1 > 1e-150) { double r = 1.0 / n1; u1[0] *= r; u1[1] *= r; u1[2] *= r; }
  else { u1[0] = 1.0; u1[1] = 0.0; u1[2] = 0.0; }

  // u2 = normalize(H v2 orthogonalized against u1)
#pragma unroll
  for (int k = 0; k < 3; ++k) u2[k] = H[k][0] * v2[0] + H[k][1] * v2[1] + H[k][2] * v2[2];
  double d12 = u1[0] * u2[0] + u1[1] * u2[1] + u1[2] * u2[2];
#pragma unroll
  for (int k = 0; k < 3; ++k) u2[k] -= d12 * u1[k];
  double n2 = sqrt(u2[0] * u2[0] + u2[1] * u2[1] + u2[2] * u2[2]);
  if (n2 > 1e-150) { double r = 1.0 / n2; u2[0] *= r; u2[1] *= r; u2[2] *= r; }
  else {
    double ax = fabs(u1[0]);
    double t0 = (ax < 0.9) ? 1.0 : 0.0, t1v = (ax < 0.9) ? 0.0 : 1.0;
    u2[0] = t0 - (t0 * u1[0] + t1v * u1[1]) * u1[0];
    u2[1] = t1v - (t0 * u1[0] + t1v * u1[1]) * u1[1];
    u2[2] = -(t0 * u1[0] + t1v * u1[1]) * u1[2];
    double nn = sqrt(u2[0] * u2[0] + u2[1] * u2[1] + u2[2] * u2[2]);
    u2[0] /= nn; u2[1] /= nn; u2[2] /= nn;
  }

  // w3 = u1 x u2 (unit, right-handed)
  double w3[3] = {u1[1] * u2[2] - u1[2] * u2[1],
                  u1[2] * u2[0] - u1[0] * u2[2],
                  u1[0] * u2[1] - u1[1] * u2[0]};

  // det(V) = v1 . (v2 x v3)
  double cx = v2[1] * v3[2] - v2[2] * v3[1];
  double cy = v2[2] * v3[0] - v2[0] * v3[2];
  double cz = v2[0] * v3[1] - v2[1] * v3[0];
  double detV = v1[0] * cx + v1[1] * cy + v1[2] * cz;
  detV = (detV >= 0.0) ? 1.0 : -1.0;

  double R[3][3];
#pragma unroll
  for (int i = 0; i < 3; ++i)
#pragma unroll
    for (int j = 0; j < 3; ++j)
      R[i][j] = v1[i] * u1[j] + v2[i] * u2[j] + detV * v3[i] * w3[j];

#pragma unroll
  for (int i = 0; i < 3; ++i) {
#pragma unroll
    for (int j = 0; j < 3; ++j) R9[3 * i + j] = (float)R[i][j];
    t3[i] = (float)(tc[i] - (R[i][0] * sc[0] + R[i][1] * sc[1] + R[i][2] * sc[2]));
  }
}

// ---------------------------------------------------------------------------
// Kernel 1: 4 blocks per batch, 1024 points per block, 4 points per thread.
// Each wave issues its 7 float4 loads exactly once -> short-lived blocks,
// continuous turnover, high outstanding-load count per CU.
// ---------------------------------------------------------------------------
__global__ __launch_bounds__(THREADS) void wp_reduce_split(const float* __restrict__ src,
                                                           const float* __restrict__ tgt,
                                                           const float* __restrict__ wts,
                                                           float* __restrict__ partials) {
  __shared__ float red[64];
  const int bid = blockIdx.x;
  const int b = bid >> 2;          // batch
  const int c = bid & 3;           // chunk within batch
  const size_t off = (size_t)b * NPTS + (size_t)c * CPTS;
  float acc[16];
  accumulate4(src + off * 3, tgt + off * 3, wts + off, acc);
  reduce_block16(acc, red);
  if (threadIdx.x == 0) {
#pragma unroll
    for (int i = 0; i < 16; ++i) partials[(size_t)bid * 16 + i] = acc[i];
  }
}

// ---------------------------------------------------------------------------
// Kernel 2: one thread per batch: sum the 4 chunk-partials, fp64 solve.
// 64-thread blocks spread the 2048 solves across 32 CUs.
// ---------------------------------------------------------------------------
__global__ __launch_bounds__(64) void wp_solve(const float* __restrict__ partials,
                                               float* __restrict__ out) {
  const int b = blockIdx.x * 64 + threadIdx.x;
  if (b >= BATCH) return;
  float acc[16];
#pragma unroll
  for (int i = 0; i < 16; ++i) acc[i] = 0.f;
#pragma unroll
  for (int cch = 0; cch < CHUNKS; ++cch)
#pragma unroll
    for (int i = 0; i < 16; ++i)
      acc[i] += partials[(size_t)(b * CHUNKS + cch) * 16 + i];
  float R9[9], t3[3];
  solve_from_acc(acc, R9, t3);
#pragma unroll
  for (int i = 0; i < 9; ++i) out[(size_t)b * 9 + i] = R9[i];
#pragma unroll
  for (int i = 0; i < 3; ++i) out[(size_t)BATCH * 9 + (size_t)b * 3 + i] = t3[i];
}

// ---------------------------------------------------------------------------
// Fused fallback (only if ws_size is too small): one block per batch.
// ---------------------------------------------------------------------------
__global__ __launch_bounds__(THREADS) void wp_fused(const float* __restrict__ src,
                                                    const float* __restrict__ tgt,
                                                    const float* __restrict__ wts,
                                                    float* __restrict__ out) {
  __shared__ float red[64];
  const int b = blockIdx.x;
  float accT[16];
  float acc[16];
#pragma unroll
  for (int i = 0; i < 16; ++i) acc[i] = 0.f;
  for (int c = 0; c < CHUNKS; ++c) {
    const size_t off = (size_t)b * NPTS + (size_t)c * CPTS;
    accumulate4(src + off * 3, tgt + off * 3, wts + off, accT);
#pragma unroll
    for (int i = 0; i < 16; ++i) acc[i] += accT[i];
  }
  reduce_block16(acc, red);
  if (threadIdx.x == 0) {
    float R9[9], t3[3];
    solve_from_acc(acc, R9, t3);
#pragma unroll
    for (int i = 0; i < 9; ++i) out[(size_t)b * 9 + i] = R9[i];
#pragma unroll
    for (int i = 0; i < 3; ++i) out[(size_t)BATCH * 9 + (size_t)b * 3 + i] = t3[i];
  }
}

extern "C" void kernel_launch(void* const* d_in, const int* in_sizes, int n_in,
                              void* d_out, int out_size, void* d_ws, size_t ws_size,
                              hipStream_t stream) {
  const float* src = (const float*)d_in[0];
  const float* tgt = (const float*)d_in[1];
  const float* wts = (const float*)d_in[2];
  float* out = (float*)d_out;

  if (ws_size >= (size_t)BATCH * CHUNKS * 16 * sizeof(float)) {
    float* partials = (float*)d_ws;
    wp_reduce_split<<<BATCH * CHUNKS, THREADS, 0, stream>>>(src, tgt, wts, partials);
    wp_solve<<<(BATCH + 63) / 64, 64, 0, stream>>>(partials, out);
  } else {
    wp_fused<<<BATCH, THREADS, 0, stream>>>(src, tgt, wts, out);
  }
}